// Round 18
// baseline (221.183 us; speedup 1.0000x reference)
//
#include <hip/hip_runtime.h>

// VGRUd v18 — v17 + FULL gate-weight matrix persistent in registers.
// 256 blocks x 512 thr (8 waves), 128 rows/block, 1 block/CU. LDS 131072 B.
// Wave w owns rows w*16..+16 (autonomous, NO barriers in the 25-step loop).
// KEY: launch_bounds(512,2) gives 256 VGPR/wave; v17 used 124 -> the 32
//   gate frags (128 VGPR) fit in the SAME occupancy tier. Gate MFMAs become
//   pure-register (no lgkmcnt waits); per-wave-step LDS reads 34 -> 12.
// Liveness control: Wd stays LDS-streamed (saves 40 regs); gates processed in
//   jt-pairs (C accum 32 regs live instead of 64): MFMA01->epi01->MFMA23->epi23.
// Numerics (= v15/v17): f16 single-plane weights (prescaled log2e/2log2e),
//   f16 single-plane h (exact f32 state in hold regs). absmax must be
//   bit-identical to v17: 2.441e-4.

typedef _Float16 f16x8 __attribute__((ext_vector_type(8)));
typedef float f32x4 __attribute__((ext_vector_type(4)));

#define TPB 512
#define LOG2E 1.44269504088896f
#define S2E   2.88539008177793f

template <int CTRL>
__device__ __forceinline__ float dppror(float x) {
  return __int_as_float(
      __builtin_amdgcn_update_dpp(0, __float_as_int(x), CTRL, 0xf, 0xf, true));
}
__device__ __forceinline__ void split8h(const float f[8], f16x8& hi, f16x8& lo) {
  #pragma unroll
  for (int j = 0; j < 8; ++j) {
    _Float16 h = (_Float16)f[j];
    hi[j] = h;
    lo[j] = (_Float16)(f[j] - (float)h);
  }
}

#define MFMA __builtin_amdgcn_mfma_f32_16x16x32_f16
#define EXP2 __builtin_amdgcn_exp2f
#define RCP  __builtin_amdgcn_rcpf

__global__ __launch_bounds__(TPB, 2) void vgru_all(
    const float* __restrict__ x, const float* __restrict__ Hin,
    const float* __restrict__ Wk, const float* __restrict__ Uk,
    const float* __restrict__ bias, const float* __restrict__ Wd,
    const float* __restrict__ bd, float* __restrict__ out)
{
  extern __shared__ float smem[];
  // floats: [0,24576) prologue chkAll (96 f16x8 frags); after prologue:
  //   gateW stage [0,8192) | wdStage [8192,8832) | h slots [24576,32768)
  float* chkAll = smem;
  unsigned short* hs = (unsigned short*)(smem + 24576);
  // wave w, buf p: hs + w*2048 + p*1024
  // element (ks,gk,row,j): ((ks*4+gk)*16+row)*8+j, col = ks*32+gk*8+j

  const int tid  = threadIdx.x;
  const int lane = tid & 63, w = tid >> 6;   // w in 0..7
  const int g = lane >> 4, n = lane & 15;
  const int blockbase = blockIdx.x * 128;
  const int myrow0 = blockbase + w * 16;
  const float* b0 = bias;
  const float* b1 = bias + 192;

  // biases bb[gate*4+jt] at col jt*16+n (prescaled); bdv[nt]
  float bb[16];
  #pragma unroll
  for (int jt = 0; jt < 4; ++jt) {
    int c = jt * 16 + n;
    bb[0 * 4 + jt] = (b0[c] + b1[c]) * LOG2E;
    bb[1 * 4 + jt] = (b0[64 + c] + b1[64 + c]) * LOG2E;
    bb[2 * 4 + jt] = b0[128 + c] * S2E;
    bb[3 * 4 + jt] = b1[128 + c] * S2E;
  }
  float bdv[5];
  #pragma unroll
  for (int nt = 0; nt < 5; ++nt) {
    int c = nt * 16 + n;
    bdv[nt] = (c < 78) ? bd[c] * LOG2E : 0.0f;
  }

  // ---- step 1 prologue: stage ALL 96 frags (K=192 stacked [Wk;Uk]) once ----
  for (int idx = tid; idx < 96 * 64; idx += TPB) {
    int fi = idx >> 6, ln = idx & 63;        // fi = t*16 + ntb
    int t = fi >> 4, ntb = fi & 15;
    int lg = ln >> 4, lnn = ln & 15;
    int c = ntb * 16 + lnn;
    float scale = (c < 128) ? LOG2E : S2E;
    f16x8 wf;
    #pragma unroll
    for (int j = 0; j < 8; ++j) {
      int k = t * 32 + lg * 8 + j;
      float v;
      if (k < 128) v = (c < 192) ? Wk[k * 192 + c] : 0.0f;
      else {
        int ku = k - 128;
        v = (c < 128) ? Uk[ku * 192 + c]
                      : ((c < 192) ? 0.0f : Uk[ku * 192 + 128 + (c - 192)]);
      }
      wf[j] = (_Float16)(v * scale);
    }
    ((f16x8*)chkAll)[fi * 64 + ln] = wf;
  }
  __syncthreads();

  f32x4 G0[16];
  #pragma unroll
  for (int ntb = 0; ntb < 16; ++ntb) {
    float bv = bb[ntb];
    G0[ntb] = (f32x4){bv, bv, bv, bv};
  }
  #pragma unroll 1
  for (int t = 0; t < 6; ++t) {
    f16x8 Ah0, Al0;
    {
      int row = myrow0 + n;
      const float* src = (t < 4)
          ? x + (size_t)row * 128 + t * 32 + g * 8
          : Hin + (size_t)row * 64 + (t - 4) * 32 + g * 8;
      float4 v0 = *(const float4*)src;
      float4 v1 = *(const float4*)(src + 4);
      float f[8] = {v0.x, v0.y, v0.z, v0.w, v1.x, v1.y, v1.z, v1.w};
      split8h(f, Ah0, Al0);
    }
    __builtin_amdgcn_s_setprio(1);
    #pragma unroll
    for (int ntb = 0; ntb < 16; ++ntb) {
      f16x8 wf = ((const f16x8*)chkAll)[(t * 16 + ntb) * 64 + lane];
      G0[ntb] = MFMA(Ah0, wf, G0[ntb], 0, 0, 0);
      G0[ntb] = MFMA(Al0, wf, G0[ntb], 0, 0, 0);
    }
    __builtin_amdgcn_s_setprio(0);
  }

  // step-1 epilogue -> hold regs + single-plane f16 h1 into my buf0 slot
  float hold[16];  // [jt*4+rr]
  {
    unsigned short* h0 = hs + w * 2048;
    #pragma unroll
    for (int jt = 0; jt < 4; ++jt) {
      const int ksw = jt >> 1;
      const int gkw = (jt & 1) * 2 + (n >> 3);
      const int jw  = n & 7;
      #pragma unroll
      for (int rr = 0; rr < 4; ++rr) {
        int lrow = g * 4 + rr;
        float h0v = Hin[(size_t)(myrow0 + lrow) * 64 + jt * 16 + n];
        float z  = RCP(1.0f + EXP2(-G0[0 * 4 + jt][rr]));
        float rg = RCP(1.0f + EXP2(-G0[1 * 4 + jt][rr]));
        float y  = G0[2 * 4 + jt][rr] + rg * G0[3 * 4 + jt][rr];
        float cand = 1.0f - 2.0f * RCP(EXP2(y) + 1.0f);
        float hv = cand + z * (h0v - cand);
        hold[jt * 4 + rr] = hv;
        int off = ((ksw * 4 + gkw) * 16 + lrow) * 8 + jw;
        h0[off] = __builtin_bit_cast(unsigned short, (_Float16)hv);
      }
    }
  }
  __syncthreads();  // all chkAll reads done -> safe to overwrite

  // ---- stage main-loop weights into LDS (then gates -> registers) ----
  for (int idx = tid; idx < 2048; idx += TPB) {
    int fi = idx >> 6, ln = idx & 63;        // fi = ntb*2+ks
    int ntb = fi >> 1, ks = fi & 1;
    int lg = ln >> 4, lnn = ln & 15;
    int c = ntb * 16 + lnn;
    float scale = (c < 128) ? LOG2E : S2E;
    f16x8 wf;
    #pragma unroll
    for (int j = 0; j < 8; ++j) {
      int k = ks * 32 + lg * 8 + j;
      float v;
      if      (c < 128) v = Wk[k * 192 + c] + Uk[k * 192 + c];
      else if (c < 192) v = Wk[k * 192 + c];
      else              v = Uk[k * 192 + 128 + (c - 192)];
      wf[j] = (_Float16)(v * scale);
    }
    ((f16x8*)smem)[fi * 64 + ln] = wf;              // gateW stage
  }
  for (int idx = tid; idx < 640; idx += TPB) {
    int fi = idx >> 6, ln = idx & 63;
    int nt = fi >> 1, ks = fi & 1;
    int lg = ln >> 4, lnn = ln & 15;
    int c = nt * 16 + lnn;
    f16x8 wf;
    #pragma unroll
    for (int j = 0; j < 8; ++j) {
      int k = ks * 32 + lg * 8 + j;
      wf[j] = (_Float16)((c < 78) ? Wd[k * 78 + c] * LOG2E : 0.0f);
    }
    ((f16x8*)(smem + 8192))[fi * 64 + ln] = wf;     // wdStage
  }
  __syncthreads();  // LAST barrier of the kernel

  // ---- persistent gate weights: ALL 32 frags -> 128 VGPR ----
  f16x8 Wg[4][4][2];  // [gg][jt][ks]
  #pragma unroll
  for (int gg = 0; gg < 4; ++gg)
    #pragma unroll
    for (int jt = 0; jt < 4; ++jt)
      #pragma unroll
      for (int ks = 0; ks < 2; ++ks)
        Wg[gg][jt][ks] = ((const f16x8*)smem)[((gg * 4 + jt) * 2 + ks) * 64 + lane];

  const f16x8* WD = (const f16x8*)(smem + 8192);

  // persistent store pointers: op[rr] -> out row (myrow0+g*4+rr), step 0, +n
  float* op0 = out + ((size_t)(myrow0 + g * 4 + 0) * 25) * 78 + n;
  float* op1 = out + ((size_t)(myrow0 + g * 4 + 1) * 25) * 78 + n;
  float* op2 = out + ((size_t)(myrow0 + g * 4 + 2) * 25) * 78 + n;
  float* op3 = out + ((size_t)(myrow0 + g * 4 + 3) * 25) * 78 + n;

  // prologue A-frag read from buf0
  f16x8 Ah[2];
  {
    const unsigned short* c0 = hs + w * 2048;
    #pragma unroll
    for (int ks = 0; ks < 2; ++ks) {
      int off = ((ks * 4 + g) * 16 + n) * 8;
      Ah[ks] = *(const f16x8*)(c0 + off);
    }
  }

  // ---- 25 iterations, barrier-free ----
  #pragma unroll 1
  for (int s = 0; s < 25; ++s) {
    unsigned short* nxt = hs + w * 2048 + ((s + 1) & 1) * 1024;
    const bool last = (s == 24);

    // ---- logits MFMA (wd streamed from LDS) ----
    f32x4 L[5];
    #pragma unroll
    for (int nt = 0; nt < 5; ++nt)
      L[nt] = (f32x4){bdv[nt], bdv[nt], bdv[nt], bdv[nt]};
    __builtin_amdgcn_s_setprio(1);
    #pragma unroll
    for (int nt = 0; nt < 5; ++nt)
      #pragma unroll
      for (int ks = 0; ks < 2; ++ks)
        L[nt] = MFMA(Ah[ks], WD[(nt * 2 + ks) * 64 + lane], L[nt], 0, 0, 0);
    __builtin_amdgcn_s_setprio(0);

    // ---- gates in jt-pairs: MFMA(pure-reg) -> epilogue -> h-writes ----
    if (!last) {
      #pragma unroll
      for (int jp = 0; jp < 2; ++jp) {      // jt = jp*2, jp*2+1
        f32x4 C[2][4];
        #pragma unroll
        for (int jl = 0; jl < 2; ++jl)
          #pragma unroll
          for (int gg = 0; gg < 4; ++gg) {
            float bv = bb[gg * 4 + (jp * 2 + jl)];
            C[jl][gg] = (f32x4){bv, bv, bv, bv};
          }
        __builtin_amdgcn_s_setprio(1);
        #pragma unroll
        for (int jl = 0; jl < 2; ++jl) {
          const int jt = jp * 2 + jl;
          #pragma unroll
          for (int ks = 0; ks < 2; ++ks) {
            C[jl][0] = MFMA(Ah[ks], Wg[0][jt][ks], C[jl][0], 0, 0, 0);
            C[jl][1] = MFMA(Ah[ks], Wg[1][jt][ks], C[jl][1], 0, 0, 0);
            C[jl][2] = MFMA(Ah[ks], Wg[2][jt][ks], C[jl][2], 0, 0, 0);
            C[jl][3] = MFMA(Ah[ks], Wg[3][jt][ks], C[jl][3], 0, 0, 0);
          }
        }
        __builtin_amdgcn_s_setprio(0);
        #pragma unroll
        for (int jl = 0; jl < 2; ++jl) {
          const int jt = jp * 2 + jl;
          const int ksw = jt >> 1;
          const int gkw = (jt & 1) * 2 + (n >> 3);
          const int jw  = n & 7;
          #pragma unroll
          for (int rr = 0; rr < 4; ++rr) {
            float z  = RCP(1.0f + EXP2(-C[jl][0][rr]));
            float rg = RCP(1.0f + EXP2(-C[jl][1][rr]));
            float y  = C[jl][2][rr] + rg * C[jl][3][rr];
            float cand = 1.0f - 2.0f * RCP(EXP2(y) + 1.0f);
            float hv = cand + z * (hold[jt * 4 + rr] - cand);
            hold[jt * 4 + rr] = hv;
            int off = ((ksw * 4 + gkw) * 16 + (g * 4 + rr)) * 8 + jw;
            nxt[off] = __builtin_bit_cast(unsigned short, (_Float16)hv);
          }
        }
      }
      // next-step A-frag reads (same-wave DS ops in order -> see the writes);
      // latency hides under softmax below.
      #pragma unroll
      for (int ks = 0; ks < 2; ++ks) {
        int off = ((ks * 4 + g) * 16 + n) * 8;
        Ah[ks] = *(const f16x8*)(nxt + off);
      }
    }

    // ---- softmax + probs stores (pointer + imm offsets) ----
    #pragma unroll
    for (int rr = 0; rr < 4; ++rr) {
      float e0 = EXP2(L[0][rr]);
      float e1 = EXP2(L[1][rr]);
      float e2 = EXP2(L[2][rr]);
      float e3 = EXP2(L[3][rr]);
      float e4 = (n < 14) ? EXP2(L[4][rr]) : 0.0f;
      float sm = e0 + e1 + e2 + e3 + e4;
      sm += dppror<0x128>(sm);
      sm += dppror<0x124>(sm);
      sm += dppror<0x122>(sm);
      sm += dppror<0x121>(sm);
      float inv = RCP(sm);
      float* orow = (rr == 0) ? op0 : (rr == 1) ? op1 : (rr == 2) ? op2 : op3;
      orow[0]  = e0 * inv;
      orow[16] = e1 * inv;
      orow[32] = e2 * inv;
      orow[48] = e3 * inv;
      if (n < 14) orow[64] = e4 * inv;
    }
    op0 += 78; op1 += 78; op2 += 78; op3 += 78;
  }
}

extern "C" void kernel_launch(void* const* d_in, const int* in_sizes, int n_in,
                              void* d_out, int out_size, void* d_ws, size_t ws_size,
                              hipStream_t stream) {
  const float* x   = (const float*)d_in[0];
  const float* H   = (const float*)d_in[1];
  const float* Wk  = (const float*)d_in[2];
  const float* Uk  = (const float*)d_in[3];
  const float* b   = (const float*)d_in[4];
  const float* Wd  = (const float*)d_in[5];
  const float* bd  = (const float*)d_in[6];
  float* out = (float*)d_out;
  (void)d_ws; (void)ws_size; (void)in_sizes; (void)n_in; (void)out_size;

  const int lds = 32768 * 4;  // 131072 B -> 1 block/CU
  hipFuncSetAttribute((const void*)vgru_all,
                      hipFuncAttributeMaxDynamicSharedMemorySize, lds);
  vgru_all<<<dim3(256), dim3(TPB), lds, stream>>>(x, H, Wk, Uk, b, Wd, bd, out);
}

// Round 19
// 172.113 us; speedup vs baseline: 1.2851x; 1.2851x over previous
//
#include <hip/hip_runtime.h>

// VGRUd v19 — v17 + HALF gate weights persistent (ks=0 slice, 64 VGPR).
// 256 blocks x 512 thr (8 waves), 128 rows/block, 1 block/CU. LDS 131072 B.
// Wave w owns rows w*16..+16 (autonomous, NO barriers in the 25-step loop).
// v18 post-mortem: full 128-reg residency spilled (peak ~270 > 256). This
//   version stays at peak ~216: Wg[4][4] (ks=0) in regs, ks=1 streamed from
//   LDS; C accum in jt-pairs (32 live); wdr persistent (40).
// Per-wave-step LDS reads 34 -> 18. Gates-first MFMA order (critical path).
// Numerics (= v15/v17): f16 single-plane weights (prescaled log2e/2log2e),
//   f16 single-plane h (exact f32 state in hold regs). absmax = 2.441e-4.

typedef _Float16 f16x8 __attribute__((ext_vector_type(8)));
typedef float f32x4 __attribute__((ext_vector_type(4)));

#define TPB 512
#define LOG2E 1.44269504088896f
#define S2E   2.88539008177793f

template <int CTRL>
__device__ __forceinline__ float dppror(float x) {
  return __int_as_float(
      __builtin_amdgcn_update_dpp(0, __float_as_int(x), CTRL, 0xf, 0xf, true));
}
__device__ __forceinline__ void split8h(const float f[8], f16x8& hi, f16x8& lo) {
  #pragma unroll
  for (int j = 0; j < 8; ++j) {
    _Float16 h = (_Float16)f[j];
    hi[j] = h;
    lo[j] = (_Float16)(f[j] - (float)h);
  }
}

#define MFMA __builtin_amdgcn_mfma_f32_16x16x32_f16
#define EXP2 __builtin_amdgcn_exp2f
#define RCP  __builtin_amdgcn_rcpf

__global__ __launch_bounds__(TPB, 2) void vgru_all(
    const float* __restrict__ x, const float* __restrict__ Hin,
    const float* __restrict__ Wk, const float* __restrict__ Uk,
    const float* __restrict__ bias, const float* __restrict__ Wd,
    const float* __restrict__ bd, float* __restrict__ out)
{
  extern __shared__ float smem[];
  // floats: [0,24576) prologue chkAll (96 f16x8 frags); after prologue:
  //   gateW stage [0,8192) | wdStage [8192,8832) | h slots [24576,32768)
  float* chkAll = smem;
  unsigned short* hs = (unsigned short*)(smem + 24576);
  // wave w, buf p: hs + w*2048 + p*1024
  // element (ks,gk,row,j): ((ks*4+gk)*16+row)*8+j, col = ks*32+gk*8+j

  const int tid  = threadIdx.x;
  const int lane = tid & 63, w = tid >> 6;   // w in 0..7
  const int g = lane >> 4, n = lane & 15;
  const int blockbase = blockIdx.x * 128;
  const int myrow0 = blockbase + w * 16;
  const float* b0 = bias;
  const float* b1 = bias + 192;

  // biases bb[gate*4+jt] at col jt*16+n (prescaled); bdv[nt]
  float bb[16];
  #pragma unroll
  for (int jt = 0; jt < 4; ++jt) {
    int c = jt * 16 + n;
    bb[0 * 4 + jt] = (b0[c] + b1[c]) * LOG2E;
    bb[1 * 4 + jt] = (b0[64 + c] + b1[64 + c]) * LOG2E;
    bb[2 * 4 + jt] = b0[128 + c] * S2E;
    bb[3 * 4 + jt] = b1[128 + c] * S2E;
  }
  float bdv[5];
  #pragma unroll
  for (int nt = 0; nt < 5; ++nt) {
    int c = nt * 16 + n;
    bdv[nt] = (c < 78) ? bd[c] * LOG2E : 0.0f;
  }

  // ---- step 1 prologue: stage ALL 96 frags (K=192 stacked [Wk;Uk]) once ----
  for (int idx = tid; idx < 96 * 64; idx += TPB) {
    int fi = idx >> 6, ln = idx & 63;        // fi = t*16 + ntb
    int t = fi >> 4, ntb = fi & 15;
    int lg = ln >> 4, lnn = ln & 15;
    int c = ntb * 16 + lnn;
    float scale = (c < 128) ? LOG2E : S2E;
    f16x8 wf;
    #pragma unroll
    for (int j = 0; j < 8; ++j) {
      int k = t * 32 + lg * 8 + j;
      float v;
      if (k < 128) v = (c < 192) ? Wk[k * 192 + c] : 0.0f;
      else {
        int ku = k - 128;
        v = (c < 128) ? Uk[ku * 192 + c]
                      : ((c < 192) ? 0.0f : Uk[ku * 192 + 128 + (c - 192)]);
      }
      wf[j] = (_Float16)(v * scale);
    }
    ((f16x8*)chkAll)[fi * 64 + ln] = wf;
  }
  __syncthreads();

  f32x4 G0[16];
  #pragma unroll
  for (int ntb = 0; ntb < 16; ++ntb) {
    float bv = bb[ntb];
    G0[ntb] = (f32x4){bv, bv, bv, bv};
  }
  #pragma unroll 1
  for (int t = 0; t < 6; ++t) {
    f16x8 Ah0, Al0;
    {
      int row = myrow0 + n;
      const float* src = (t < 4)
          ? x + (size_t)row * 128 + t * 32 + g * 8
          : Hin + (size_t)row * 64 + (t - 4) * 32 + g * 8;
      float4 v0 = *(const float4*)src;
      float4 v1 = *(const float4*)(src + 4);
      float f[8] = {v0.x, v0.y, v0.z, v0.w, v1.x, v1.y, v1.z, v1.w};
      split8h(f, Ah0, Al0);
    }
    __builtin_amdgcn_s_setprio(1);
    #pragma unroll
    for (int ntb = 0; ntb < 16; ++ntb) {
      f16x8 wf = ((const f16x8*)chkAll)[(t * 16 + ntb) * 64 + lane];
      G0[ntb] = MFMA(Ah0, wf, G0[ntb], 0, 0, 0);
      G0[ntb] = MFMA(Al0, wf, G0[ntb], 0, 0, 0);
    }
    __builtin_amdgcn_s_setprio(0);
  }

  // step-1 epilogue -> hold regs + single-plane f16 h1 into my buf0 slot
  float hold[16];  // [jt*4+rr]
  {
    unsigned short* h0 = hs + w * 2048;
    #pragma unroll
    for (int jt = 0; jt < 4; ++jt) {
      const int ksw = jt >> 1;
      const int gkw = (jt & 1) * 2 + (n >> 3);
      const int jw  = n & 7;
      #pragma unroll
      for (int rr = 0; rr < 4; ++rr) {
        int lrow = g * 4 + rr;
        float h0v = Hin[(size_t)(myrow0 + lrow) * 64 + jt * 16 + n];
        float z  = RCP(1.0f + EXP2(-G0[0 * 4 + jt][rr]));
        float rg = RCP(1.0f + EXP2(-G0[1 * 4 + jt][rr]));
        float y  = G0[2 * 4 + jt][rr] + rg * G0[3 * 4 + jt][rr];
        float cand = 1.0f - 2.0f * RCP(EXP2(y) + 1.0f);
        float hv = cand + z * (h0v - cand);
        hold[jt * 4 + rr] = hv;
        int off = ((ksw * 4 + gkw) * 16 + lrow) * 8 + jw;
        h0[off] = __builtin_bit_cast(unsigned short, (_Float16)hv);
      }
    }
  }
  __syncthreads();  // all chkAll reads done -> safe to overwrite

  // ---- stage main-loop weights into LDS ----
  for (int idx = tid; idx < 2048; idx += TPB) {
    int fi = idx >> 6, ln = idx & 63;        // fi = ntb*2+ks
    int ntb = fi >> 1, ks = fi & 1;
    int lg = ln >> 4, lnn = ln & 15;
    int c = ntb * 16 + lnn;
    float scale = (c < 128) ? LOG2E : S2E;
    f16x8 wf;
    #pragma unroll
    for (int j = 0; j < 8; ++j) {
      int k = ks * 32 + lg * 8 + j;
      float v;
      if      (c < 128) v = Wk[k * 192 + c] + Uk[k * 192 + c];
      else if (c < 192) v = Wk[k * 192 + c];
      else              v = Uk[k * 192 + 128 + (c - 192)];
      wf[j] = (_Float16)(v * scale);
    }
    ((f16x8*)smem)[fi * 64 + ln] = wf;              // gateW stage
  }
  for (int idx = tid; idx < 640; idx += TPB) {
    int fi = idx >> 6, ln = idx & 63;
    int nt = fi >> 1, ks = fi & 1;
    int lg = ln >> 4, lnn = ln & 15;
    int c = nt * 16 + lnn;
    f16x8 wf;
    #pragma unroll
    for (int j = 0; j < 8; ++j) {
      int k = ks * 32 + lg * 8 + j;
      wf[j] = (_Float16)((c < 78) ? Wd[k * 78 + c] * LOG2E : 0.0f);
    }
    ((f16x8*)(smem + 8192))[fi * 64 + ln] = wf;     // wdStage
  }
  __syncthreads();  // LAST barrier of the kernel

  const f16x8* GW = (const f16x8*)smem;
  // persistent: ks=0 gate frags (16 = 64 VGPR) + Wd (10 = 40 VGPR)
  f16x8 Wg[4][4];  // [gg][jt], ks=0 slice
  #pragma unroll
  for (int gg = 0; gg < 4; ++gg)
    #pragma unroll
    for (int jt = 0; jt < 4; ++jt)
      Wg[gg][jt] = GW[((gg * 4 + jt) * 2 + 0) * 64 + lane];
  f16x8 wdr[5][2];
  #pragma unroll
  for (int nt = 0; nt < 5; ++nt)
    #pragma unroll
    for (int ks = 0; ks < 2; ++ks)
      wdr[nt][ks] = ((const f16x8*)(smem + 8192))[(nt * 2 + ks) * 64 + lane];

  // persistent store pointers: op[rr] -> out row (myrow0+g*4+rr), step 0, +n
  float* op0 = out + ((size_t)(myrow0 + g * 4 + 0) * 25) * 78 + n;
  float* op1 = out + ((size_t)(myrow0 + g * 4 + 1) * 25) * 78 + n;
  float* op2 = out + ((size_t)(myrow0 + g * 4 + 2) * 25) * 78 + n;
  float* op3 = out + ((size_t)(myrow0 + g * 4 + 3) * 25) * 78 + n;

  // prologue A-frag read from buf0
  f16x8 Ah[2];
  {
    const unsigned short* c0 = hs + w * 2048;
    #pragma unroll
    for (int ks = 0; ks < 2; ++ks) {
      int off = ((ks * 4 + g) * 16 + n) * 8;
      Ah[ks] = *(const f16x8*)(c0 + off);
    }
  }

  // ---- 25 iterations, barrier-free ----
  #pragma unroll 1
  for (int s = 0; s < 25; ++s) {
    unsigned short* nxt = hs + w * 2048 + ((s + 1) & 1) * 1024;
    const bool last = (s == 24);

    // ---- gates in jt-pairs (critical path): ks=0 reg-fed, ks=1 LDS ----
    if (!last) {
      #pragma unroll
      for (int jp = 0; jp < 2; ++jp) {      // jt = jp*2, jp*2+1
        f32x4 C[2][4];
        #pragma unroll
        for (int jl = 0; jl < 2; ++jl)
          #pragma unroll
          for (int gg = 0; gg < 4; ++gg) {
            float bv = bb[gg * 4 + (jp * 2 + jl)];
            C[jl][gg] = (f32x4){bv, bv, bv, bv};
          }
        __builtin_amdgcn_s_setprio(1);
        #pragma unroll
        for (int jl = 0; jl < 2; ++jl) {
          const int jt = jp * 2 + jl;
          C[jl][0] = MFMA(Ah[0], Wg[0][jt], C[jl][0], 0, 0, 0);
          C[jl][1] = MFMA(Ah[0], Wg[1][jt], C[jl][1], 0, 0, 0);
          C[jl][2] = MFMA(Ah[0], Wg[2][jt], C[jl][2], 0, 0, 0);
          C[jl][3] = MFMA(Ah[0], Wg[3][jt], C[jl][3], 0, 0, 0);
          C[jl][0] = MFMA(Ah[1], GW[((0 * 4 + jt) * 2 + 1) * 64 + lane], C[jl][0], 0, 0, 0);
          C[jl][1] = MFMA(Ah[1], GW[((1 * 4 + jt) * 2 + 1) * 64 + lane], C[jl][1], 0, 0, 0);
          C[jl][2] = MFMA(Ah[1], GW[((2 * 4 + jt) * 2 + 1) * 64 + lane], C[jl][2], 0, 0, 0);
          C[jl][3] = MFMA(Ah[1], GW[((3 * 4 + jt) * 2 + 1) * 64 + lane], C[jl][3], 0, 0, 0);
        }
        __builtin_amdgcn_s_setprio(0);
        #pragma unroll
        for (int jl = 0; jl < 2; ++jl) {
          const int jt = jp * 2 + jl;
          const int ksw = jt >> 1;
          const int gkw = (jt & 1) * 2 + (n >> 3);
          const int jw  = n & 7;
          #pragma unroll
          for (int rr = 0; rr < 4; ++rr) {
            float z  = RCP(1.0f + EXP2(-C[jl][0][rr]));
            float rg = RCP(1.0f + EXP2(-C[jl][1][rr]));
            float y  = C[jl][2][rr] + rg * C[jl][3][rr];
            float cand = 1.0f - 2.0f * RCP(EXP2(y) + 1.0f);
            float hv = cand + z * (hold[jt * 4 + rr] - cand);
            hold[jt * 4 + rr] = hv;
            int off = ((ksw * 4 + gkw) * 16 + (g * 4 + rr)) * 8 + jw;
            nxt[off] = __builtin_bit_cast(unsigned short, (_Float16)hv);
          }
        }
      }
    }

    // ---- logits MFMA (persistent wdr; uses current Ah before prefetch) ----
    f32x4 L[5];
    #pragma unroll
    for (int nt = 0; nt < 5; ++nt)
      L[nt] = (f32x4){bdv[nt], bdv[nt], bdv[nt], bdv[nt]};
    __builtin_amdgcn_s_setprio(1);
    #pragma unroll
    for (int nt = 0; nt < 5; ++nt)
      #pragma unroll
      for (int ks = 0; ks < 2; ++ks)
        L[nt] = MFMA(Ah[ks], wdr[nt][ks], L[nt], 0, 0, 0);
    __builtin_amdgcn_s_setprio(0);

    // ---- next-step A-frag prefetch (sees this step's h-writes) ----
    if (!last) {
      #pragma unroll
      for (int ks = 0; ks < 2; ++ks) {
        int off = ((ks * 4 + g) * 16 + n) * 8;
        Ah[ks] = *(const f16x8*)(nxt + off);
      }
    }

    // ---- softmax + probs stores (pointer + imm offsets) ----
    #pragma unroll
    for (int rr = 0; rr < 4; ++rr) {
      float e0 = EXP2(L[0][rr]);
      float e1 = EXP2(L[1][rr]);
      float e2 = EXP2(L[2][rr]);
      float e3 = EXP2(L[3][rr]);
      float e4 = (n < 14) ? EXP2(L[4][rr]) : 0.0f;
      float sm = e0 + e1 + e2 + e3 + e4;
      sm += dppror<0x128>(sm);
      sm += dppror<0x124>(sm);
      sm += dppror<0x122>(sm);
      sm += dppror<0x121>(sm);
      float inv = RCP(sm);
      float* orow = (rr == 0) ? op0 : (rr == 1) ? op1 : (rr == 2) ? op2 : op3;
      orow[0]  = e0 * inv;
      orow[16] = e1 * inv;
      orow[32] = e2 * inv;
      orow[48] = e3 * inv;
      if (n < 14) orow[64] = e4 * inv;
    }
    op0 += 78; op1 += 78; op2 += 78; op3 += 78;
  }
}

extern "C" void kernel_launch(void* const* d_in, const int* in_sizes, int n_in,
                              void* d_out, int out_size, void* d_ws, size_t ws_size,
                              hipStream_t stream) {
  const float* x   = (const float*)d_in[0];
  const float* H   = (const float*)d_in[1];
  const float* Wk  = (const float*)d_in[2];
  const float* Uk  = (const float*)d_in[3];
  const float* b   = (const float*)d_in[4];
  const float* Wd  = (const float*)d_in[5];
  const float* bd  = (const float*)d_in[6];
  float* out = (float*)d_out;
  (void)d_ws; (void)ws_size; (void)in_sizes; (void)n_in; (void)out_size;

  const int lds = 32768 * 4;  // 131072 B -> 1 block/CU
  hipFuncSetAttribute((const void*)vgru_all,
                      hipFuncAttributeMaxDynamicSharedMemorySize, lds);
  vgru_all<<<dim3(256), dim3(TPB), lds, stream>>>(x, H, Wk, Uk, b, Wd, bd, out);
}

// Round 20
// 112.140 us; speedup vs baseline: 1.9724x; 1.5348x over previous
//
#include <hip/hip_runtime.h>

// VGRUd v20 == v17 (measured best: 112.5 µs wall, absmax 2.441e-4). Restored
// after v18/v19 register-residency attempts both spilled (VGPR tier pinned at
// 128; persistent gate weights beyond Wd do not fit — falsified 5x).
// 256 blocks x 512 thr (8 waves), 128 rows/block, 1 block/CU. LDS 131072 B.
// Wave w owns rows w*16..+16 (autonomous, NO barriers in the 25-step loop).
// Numerics: f16 single-plane weights (prescaled log2e / 2log2e); f16
//   single-plane h in LDS (exact f32 state in hold regs); Wd in VGPRs (40).
// Pipeline: gates MFMA -> logits MFMA -> gate epilogue + h-writes ->
//   next-step A-prefetch -> softmax + pointer-increment probs stores.

typedef _Float16 f16x8 __attribute__((ext_vector_type(8)));
typedef float f32x4 __attribute__((ext_vector_type(4)));

#define TPB 512
#define LOG2E 1.44269504088896f
#define S2E   2.88539008177793f

template <int CTRL>
__device__ __forceinline__ float dppror(float x) {
  return __int_as_float(
      __builtin_amdgcn_update_dpp(0, __float_as_int(x), CTRL, 0xf, 0xf, true));
}
__device__ __forceinline__ void split8h(const float f[8], f16x8& hi, f16x8& lo) {
  #pragma unroll
  for (int j = 0; j < 8; ++j) {
    _Float16 h = (_Float16)f[j];
    hi[j] = h;
    lo[j] = (_Float16)(f[j] - (float)h);
  }
}

#define MFMA __builtin_amdgcn_mfma_f32_16x16x32_f16
#define EXP2 __builtin_amdgcn_exp2f
#define RCP  __builtin_amdgcn_rcpf

__global__ __launch_bounds__(TPB, 2) void vgru_all(
    const float* __restrict__ x, const float* __restrict__ Hin,
    const float* __restrict__ Wk, const float* __restrict__ Uk,
    const float* __restrict__ bias, const float* __restrict__ Wd,
    const float* __restrict__ bd, float* __restrict__ out)
{
  extern __shared__ float smem[];
  // floats: [0,24576) prologue chkAll (96 f16x8 frags); after prologue:
  //   gateW [0,8192) (32 frags) | wdStage [8192,8832) | h slots [24576,32768)
  float* chkAll = smem;
  unsigned short* hs = (unsigned short*)(smem + 24576);
  // wave w, buf p: hs + w*2048 + p*1024
  // element (ks,gk,row,j): ((ks*4+gk)*16+row)*8+j, col = ks*32+gk*8+j

  const int tid  = threadIdx.x;
  const int lane = tid & 63, w = tid >> 6;   // w in 0..7
  const int g = lane >> 4, n = lane & 15;
  const int blockbase = blockIdx.x * 128;
  const int myrow0 = blockbase + w * 16;
  const float* b0 = bias;
  const float* b1 = bias + 192;

  // biases bb[gate*4+jt] at col jt*16+n (prescaled); bdv[nt]
  float bb[16];
  #pragma unroll
  for (int jt = 0; jt < 4; ++jt) {
    int c = jt * 16 + n;
    bb[0 * 4 + jt] = (b0[c] + b1[c]) * LOG2E;
    bb[1 * 4 + jt] = (b0[64 + c] + b1[64 + c]) * LOG2E;
    bb[2 * 4 + jt] = b0[128 + c] * S2E;
    bb[3 * 4 + jt] = b1[128 + c] * S2E;
  }
  float bdv[5];
  #pragma unroll
  for (int nt = 0; nt < 5; ++nt) {
    int c = nt * 16 + n;
    bdv[nt] = (c < 78) ? bd[c] * LOG2E : 0.0f;
  }

  // ---- step 1 prologue: stage ALL 96 frags (K=192 stacked [Wk;Uk]) once ----
  for (int idx = tid; idx < 96 * 64; idx += TPB) {
    int fi = idx >> 6, ln = idx & 63;        // fi = t*16 + ntb
    int t = fi >> 4, ntb = fi & 15;
    int lg = ln >> 4, lnn = ln & 15;
    int c = ntb * 16 + lnn;
    float scale = (c < 128) ? LOG2E : S2E;
    f16x8 wf;
    #pragma unroll
    for (int j = 0; j < 8; ++j) {
      int k = t * 32 + lg * 8 + j;
      float v;
      if (k < 128) v = (c < 192) ? Wk[k * 192 + c] : 0.0f;
      else {
        int ku = k - 128;
        v = (c < 128) ? Uk[ku * 192 + c]
                      : ((c < 192) ? 0.0f : Uk[ku * 192 + 128 + (c - 192)]);
      }
      wf[j] = (_Float16)(v * scale);
    }
    ((f16x8*)chkAll)[fi * 64 + ln] = wf;
  }
  __syncthreads();

  f32x4 G0[16];
  #pragma unroll
  for (int ntb = 0; ntb < 16; ++ntb) {
    float bv = bb[ntb];
    G0[ntb] = (f32x4){bv, bv, bv, bv};
  }
  #pragma unroll 1
  for (int t = 0; t < 6; ++t) {
    f16x8 Ah0, Al0;
    {
      int row = myrow0 + n;
      const float* src = (t < 4)
          ? x + (size_t)row * 128 + t * 32 + g * 8
          : Hin + (size_t)row * 64 + (t - 4) * 32 + g * 8;
      float4 v0 = *(const float4*)src;
      float4 v1 = *(const float4*)(src + 4);
      float f[8] = {v0.x, v0.y, v0.z, v0.w, v1.x, v1.y, v1.z, v1.w};
      split8h(f, Ah0, Al0);
    }
    __builtin_amdgcn_s_setprio(1);
    #pragma unroll
    for (int ntb = 0; ntb < 16; ++ntb) {
      f16x8 wf = ((const f16x8*)chkAll)[(t * 16 + ntb) * 64 + lane];
      G0[ntb] = MFMA(Ah0, wf, G0[ntb], 0, 0, 0);
      G0[ntb] = MFMA(Al0, wf, G0[ntb], 0, 0, 0);
    }
    __builtin_amdgcn_s_setprio(0);
  }

  // step-1 epilogue -> hold regs + single-plane f16 h1 into my buf0 slot
  float hold[16];  // [jt*4+rr]
  {
    unsigned short* h0 = hs + w * 2048;
    #pragma unroll
    for (int jt = 0; jt < 4; ++jt) {
      const int ksw = jt >> 1;
      const int gkw = (jt & 1) * 2 + (n >> 3);
      const int jw  = n & 7;
      #pragma unroll
      for (int rr = 0; rr < 4; ++rr) {
        int lrow = g * 4 + rr;
        float h0v = Hin[(size_t)(myrow0 + lrow) * 64 + jt * 16 + n];
        float z  = RCP(1.0f + EXP2(-G0[0 * 4 + jt][rr]));
        float rg = RCP(1.0f + EXP2(-G0[1 * 4 + jt][rr]));
        float y  = G0[2 * 4 + jt][rr] + rg * G0[3 * 4 + jt][rr];
        float cand = 1.0f - 2.0f * RCP(EXP2(y) + 1.0f);
        float hv = cand + z * (h0v - cand);
        hold[jt * 4 + rr] = hv;
        int off = ((ksw * 4 + gkw) * 16 + lrow) * 8 + jw;
        h0[off] = __builtin_bit_cast(unsigned short, (_Float16)hv);
      }
    }
  }
  __syncthreads();  // all chkAll reads done -> safe to overwrite

  // ---- stage main-loop weights ----
  for (int idx = tid; idx < 2048; idx += TPB) {
    int fi = idx >> 6, ln = idx & 63;        // fi = ntb*2+ks
    int ntb = fi >> 1, ks = fi & 1;
    int lg = ln >> 4, lnn = ln & 15;
    int c = ntb * 16 + lnn;
    float scale = (c < 128) ? LOG2E : S2E;
    f16x8 wf;
    #pragma unroll
    for (int j = 0; j < 8; ++j) {
      int k = ks * 32 + lg * 8 + j;
      float v;
      if      (c < 128) v = Wk[k * 192 + c] + Uk[k * 192 + c];
      else if (c < 192) v = Wk[k * 192 + c];
      else              v = Uk[k * 192 + 128 + (c - 192)];
      wf[j] = (_Float16)(v * scale);
    }
    ((f16x8*)smem)[fi * 64 + ln] = wf;              // gateW
  }
  for (int idx = tid; idx < 640; idx += TPB) {
    int fi = idx >> 6, ln = idx & 63;
    int nt = fi >> 1, ks = fi & 1;
    int lg = ln >> 4, lnn = ln & 15;
    int c = nt * 16 + lnn;
    f16x8 wf;
    #pragma unroll
    for (int j = 0; j < 8; ++j) {
      int k = ks * 32 + lg * 8 + j;
      wf[j] = (_Float16)((c < 78) ? Wd[k * 78 + c] * LOG2E : 0.0f);
    }
    ((f16x8*)(smem + 8192))[fi * 64 + ln] = wf;     // wdStage
  }
  __syncthreads();  // LAST barrier of the kernel

  const f16x8* GW = (const f16x8*)smem;
  f16x8 wdr[5][2];  // persistent Wd (40 VGPR)
  #pragma unroll
  for (int nt = 0; nt < 5; ++nt)
    #pragma unroll
    for (int ks = 0; ks < 2; ++ks)
      wdr[nt][ks] = ((const f16x8*)(smem + 8192))[(nt * 2 + ks) * 64 + lane];

  // persistent store pointers: op[rr] -> out row (myrow0+g*4+rr), step 0, +n
  float* op0 = out + ((size_t)(myrow0 + g * 4 + 0) * 25) * 78 + n;
  float* op1 = out + ((size_t)(myrow0 + g * 4 + 1) * 25) * 78 + n;
  float* op2 = out + ((size_t)(myrow0 + g * 4 + 2) * 25) * 78 + n;
  float* op3 = out + ((size_t)(myrow0 + g * 4 + 3) * 25) * 78 + n;

  // prologue A-frag read from buf0
  f16x8 Ah[2];
  {
    const unsigned short* c0 = hs + w * 2048;
    #pragma unroll
    for (int ks = 0; ks < 2; ++ks) {
      int off = ((ks * 4 + g) * 16 + n) * 8;
      Ah[ks] = *(const f16x8*)(c0 + off);
    }
  }

  // ---- 25 iterations, barrier-free, pipelined ----
  #pragma unroll 1
  for (int s = 0; s < 25; ++s) {
    unsigned short* nxt = hs + w * 2048 + ((s + 1) & 1) * 1024;
    const bool last = (s == 24);

    // ---- MFMA region: gates first (critical path), then logits ----
    f32x4 C[4][4];   // [jt][gate]
    #pragma unroll
    for (int jt = 0; jt < 4; ++jt)
      #pragma unroll
      for (int gg = 0; gg < 4; ++gg) {
        float bv = bb[gg * 4 + jt];
        C[jt][gg] = (f32x4){bv, bv, bv, bv};
      }
    f32x4 L[5];
    #pragma unroll
    for (int nt = 0; nt < 5; ++nt)
      L[nt] = (f32x4){bdv[nt], bdv[nt], bdv[nt], bdv[nt]};

    __builtin_amdgcn_s_setprio(1);
    if (!last) {
      #pragma unroll
      for (int jt = 0; jt < 4; ++jt)
        #pragma unroll
        for (int ks = 0; ks < 2; ++ks) {
          f16x8 w0 = GW[((0 * 4 + jt) * 2 + ks) * 64 + lane];
          f16x8 w1 = GW[((1 * 4 + jt) * 2 + ks) * 64 + lane];
          f16x8 w2 = GW[((2 * 4 + jt) * 2 + ks) * 64 + lane];
          f16x8 w3 = GW[((3 * 4 + jt) * 2 + ks) * 64 + lane];
          C[jt][0] = MFMA(Ah[ks], w0, C[jt][0], 0, 0, 0);
          C[jt][1] = MFMA(Ah[ks], w1, C[jt][1], 0, 0, 0);
          C[jt][2] = MFMA(Ah[ks], w2, C[jt][2], 0, 0, 0);
          C[jt][3] = MFMA(Ah[ks], w3, C[jt][3], 0, 0, 0);
        }
    }
    #pragma unroll
    for (int nt = 0; nt < 5; ++nt)
      #pragma unroll
      for (int ks = 0; ks < 2; ++ks)
        L[nt] = MFMA(Ah[ks], wdr[nt][ks], L[nt], 0, 0, 0);
    __builtin_amdgcn_s_setprio(0);

    // ---- gate epilogue + h-writes (critical path), then A-prefetch ----
    if (!last) {
      #pragma unroll
      for (int jt = 0; jt < 4; ++jt) {
        const int ksw = jt >> 1;
        const int gkw = (jt & 1) * 2 + (n >> 3);
        const int jw  = n & 7;
        #pragma unroll
        for (int rr = 0; rr < 4; ++rr) {
          float z  = RCP(1.0f + EXP2(-C[jt][0][rr]));
          float rg = RCP(1.0f + EXP2(-C[jt][1][rr]));
          float y  = C[jt][2][rr] + rg * C[jt][3][rr];
          float cand = 1.0f - 2.0f * RCP(EXP2(y) + 1.0f);
          float hv = cand + z * (hold[jt * 4 + rr] - cand);
          hold[jt * 4 + rr] = hv;
          int off = ((ksw * 4 + gkw) * 16 + (g * 4 + rr)) * 8 + jw;
          nxt[off] = __builtin_bit_cast(unsigned short, (_Float16)hv);
        }
      }
      // next-step A-frag reads (same-wave DS ops in order -> see the writes);
      // latency hides under softmax below.
      #pragma unroll
      for (int ks = 0; ks < 2; ++ks) {
        int off = ((ks * 4 + g) * 16 + n) * 8;
        Ah[ks] = *(const f16x8*)(nxt + off);
      }
    }

    // ---- softmax + probs stores (pointer + imm offsets) ----
    #pragma unroll
    for (int rr = 0; rr < 4; ++rr) {
      float e0 = EXP2(L[0][rr]);
      float e1 = EXP2(L[1][rr]);
      float e2 = EXP2(L[2][rr]);
      float e3 = EXP2(L[3][rr]);
      float e4 = (n < 14) ? EXP2(L[4][rr]) : 0.0f;
      float sm = e0 + e1 + e2 + e3 + e4;
      sm += dppror<0x128>(sm);
      sm += dppror<0x124>(sm);
      sm += dppror<0x122>(sm);
      sm += dppror<0x121>(sm);
      float inv = RCP(sm);
      float* orow = (rr == 0) ? op0 : (rr == 1) ? op1 : (rr == 2) ? op2 : op3;
      orow[0]  = e0 * inv;
      orow[16] = e1 * inv;
      orow[32] = e2 * inv;
      orow[48] = e3 * inv;
      if (n < 14) orow[64] = e4 * inv;
    }
    op0 += 78; op1 += 78; op2 += 78; op3 += 78;
  }
}

extern "C" void kernel_launch(void* const* d_in, const int* in_sizes, int n_in,
                              void* d_out, int out_size, void* d_ws, size_t ws_size,
                              hipStream_t stream) {
  const float* x   = (const float*)d_in[0];
  const float* H   = (const float*)d_in[1];
  const float* Wk  = (const float*)d_in[2];
  const float* Uk  = (const float*)d_in[3];
  const float* b   = (const float*)d_in[4];
  const float* Wd  = (const float*)d_in[5];
  const float* bd  = (const float*)d_in[6];
  float* out = (float*)d_out;
  (void)d_ws; (void)ws_size; (void)in_sizes; (void)n_in; (void)out_size;

  const int lds = 32768 * 4;  // 131072 B -> 1 block/CU
  hipFuncSetAttribute((const void*)vgru_all,
                      hipFuncAttributeMaxDynamicSharedMemorySize, lds);
  vgru_all<<<dim3(256), dim3(TPB), lds, stream>>>(x, H, Wk, Uk, b, Wd, bd, out);
}